// Round 16
// baseline (34.433 us; speedup 1.0000x reference)
//
#include <hip/hip_runtime.h>
#include <hip/hip_bf16.h>

typedef __bf16 bf16x8 __attribute__((ext_vector_type(8)));
typedef float  f32x4  __attribute__((ext_vector_type(4)));

#define B_ROWS 8192
#define IN_DIM 256
#define OUT_DIM 32
#define NCLS 50
#define INV_T (1.0f / 0.6f)

#define CVT_BLOCKS 1024  // x cvt: 8192*256 / (256*8)
#define GGRID 1024       // gemm grid: exactly 4 blocks/CU
#define NGRP 13          // class groups (12x4 + 1x2)
#define OSTRIDE (NCLS * OUT_DIM)   // 1600 floats per out row

__device__ __forceinline__ void gload_lds16(const void* g, void* l) {
    __builtin_amdgcn_global_load_lds(
        (const __attribute__((address_space(1))) void*)g,
        (__attribute__((address_space(3))) void*)l, 16, 0, 0);
}

// prep (r14 verbatim): blocks [0,50) W-class; blocks [50,1074) x cvt.
__global__ __launch_bounds__(256) void prep(const float* __restrict__ x,
                                            const float* __restrict__ w,
                                            __bf16* __restrict__ xb,
                                            __bf16* __restrict__ wb) {
    __shared__ float wm[4];
    int bid = blockIdx.x;
    if (bid < NCLS) {
        int c = bid;
        int i = threadIdx.x;
        const float* wc = w + (size_t)c * OUT_DIM * IN_DIM + i;
        float wv[OUT_DIM];
#pragma unroll
        for (int o = 0; o < OUT_DIM; ++o) wv[o] = wc[o * IN_DIM];
        float gsum = 0.f;
#pragma unroll
        for (int o = 0; o < OUT_DIM; ++o) gsum += fabsf(wv[o]);
        float m = gsum;
#pragma unroll
        for (int s = 1; s < 64; s <<= 1) m = fmaxf(m, __shfl_xor(m, s));
        if ((threadIdx.x & 63) == 0) wm[threadIdx.x >> 6] = m;
        __syncthreads();
        m = fmaxf(fmaxf(wm[0], wm[1]), fmaxf(wm[2], wm[3]));
        float an = __expf((gsum - m) * INV_T);
        __bf16* wo = wb + (size_t)c * OUT_DIM * IN_DIM + i;
#pragma unroll
        for (int o = 0; o < OUT_DIM; ++o)
            wo[o * IN_DIM] = (__bf16)(wv[o] * an);
    } else {
        int i = ((bid - NCLS) * 256 + threadIdx.x) * 8;
        float4 v0 = *reinterpret_cast<const float4*>(x + i);
        float4 v1 = *reinterpret_cast<const float4*>(x + i + 4);
        bf16x8 r;
        r[0] = (__bf16)v0.x; r[1] = (__bf16)v0.y; r[2] = (__bf16)v0.z; r[3] = (__bf16)v0.w;
        r[4] = (__bf16)v1.x; r[5] = (__bf16)v1.y; r[6] = (__bf16)v1.z; r[7] = (__bf16)v1.w;
        *reinterpret_cast<bf16x8*>(xb + i) = r;
    }
}

// GEMM: out[b,c,o] = sum_i xb[b,i]*wb[c,o,i] + bias[c,o]
// Shared-A design: block = 4 waves, wave w -> ONE class (group cg, class
// cg*4+w; group 12 has 2 classes, waves 2/3 duplicate — identical values).
// W' (16 frags = 64 VGPR) + bias loaded direct->regs, pinned, drained.
// A chunk (16 rows, 8 KB) staged ONCE per block into a 4-buffer LDS ring;
// staging split across waves (2 gload_lds each). Ring: stage chunk k+2 into
// buf (k+2)&3 at top of iter k; any wave still computing chunk k-1 uses buf
// (k-1)&3 = (k+3)&3 != (k+2)&3 -> race-free with ONE raw s_barrier/iter.
// Own-wave counted vmcnt before the barrier publishes each wave's 2 loads:
//   k=0: VMW(4), k=1: VMW(6), k>=2: VMW(8)  (2 loads + 2 stores per iter).
// LDS swizzle (both sides): phys 16B-slot s of row r holds logical s^r.
// Rows balanced fractionally across the 78-79 blocks of each class group.
__global__ __launch_bounds__(256, 4) void gemm(const __bf16* __restrict__ xb,
                                               const __bf16* __restrict__ wb,
                                               const float* __restrict__ bias,
                                               float* __restrict__ out) {
    __shared__ __align__(16) char lds[4 * 8192];   // 4 shared chunk buffers

    int bid = blockIdx.x;
    int cg = (bid * NGRP) >> 10;                   // class group 0..12
    int first = (cg * GGRID + NGRP - 1) / NGRP;
    int next  = ((cg + 1) * GGRID + NGRP - 1) / NGRP;
    int j = bid - first;
    int np = next - first;                         // 78 or 79
    int u0 = (j * 512) / np;                       // 16-row units [0,512)
    int u1 = ((j + 1) * 512) / np;
    int nch = u1 - u0;                             // 6..7 chunks

    int lane = threadIdx.x & 63;
    int w4 = threadIdx.x >> 6;
    int c = cg * 4 + ((cg == NGRP - 1) ? (w4 & 1) : w4);
    int l15 = lane & 15;
    int g = lane >> 4;
    int s31 = lane & 31;
    int lr = lane >> 5;

    // --- W' (1 class) + bias direct global -> pinned regs ---
    const __bf16* wp = wb + ((size_t)c * OUT_DIM + l15) * IN_DIM + g * 8;
    bf16x8 W[16];
#pragma unroll
    for (int kk = 0; kk < 8; ++kk) {
        W[kk]     = *reinterpret_cast<const bf16x8*>(wp + kk * 32);
        W[8 + kk] = *reinterpret_cast<const bf16x8*>(wp + 16 * IN_DIM + kk * 32);
    }
    f32x4 bv0 = *reinterpret_cast<const f32x4*>(bias + c * OUT_DIM + g * 4);
    f32x4 bv1 = *reinterpret_cast<const f32x4*>(bias + c * OUT_DIM + 16 + g * 4);
#pragma unroll
    for (int kk = 0; kk < 16; ++kk)
        asm volatile("" : "+v"(W[kk]));
    asm volatile("" : "+v"(bv0), "+v"(bv1));
    asm volatile("s_waitcnt vmcnt(0)" ::: "memory");
    __builtin_amdgcn_sched_barrier(0);

    const char* arows = (const char*)xb + (size_t)u0 * 16 * 512;

    // wave w4 stages rows [w4*4, w4*4+4) of chunk CH: 2 instrs x 1 KB
#define STAGE(BUF, CH)                                                            \
    _Pragma("unroll") for (int i2 = 0; i2 < 2; ++i2) {                            \
        int re = w4 * 4 + 2 * i2;                                                 \
        int r = re + lr;                                                          \
        gload_lds16(arows + (size_t)(CH) * 8192 + (size_t)r * 512 + ((s31 ^ r) * 16), \
                    (BUF) + re * 512);                                            \
    }
#define VMW(N) asm volatile("s_waitcnt vmcnt(" #N ")" ::: "memory")

    STAGE(lds, 0)
    STAGE(lds + 8192, 1)

    float* orow = out + (size_t)(u0 * 16 + l15) * OSTRIDE + c * OUT_DIM + g * 4;

    for (int k = 0; k < nch; ++k) {
        char* sb = lds + ((k + 2) & 3) * 8192;
        STAGE(sb, k + 2)                 // unconditional; overshoot lands in wb region (harmless)
        if (k == 0)      VMW(4);
        else if (k == 1) VMW(6);
        else             VMW(8);
        __builtin_amdgcn_sched_barrier(0);
        __builtin_amdgcn_s_barrier();    // raw: loads stay in flight
        __builtin_amdgcn_sched_barrier(0);

        const char* cb = lds + (k & 3) * 8192;
        f32x4 acc0 = bv0;
        f32x4 acc1 = bv1;
#pragma unroll
        for (int kk = 0; kk < 8; ++kk) {
            bf16x8 a = *reinterpret_cast<const bf16x8*>(
                cb + (size_t)l15 * 512 + (((4 * kk + g) ^ l15) * 16));
            acc0 = __builtin_amdgcn_mfma_f32_16x16x32_bf16(W[kk],     a, acc0, 0, 0, 0);
            acc1 = __builtin_amdgcn_mfma_f32_16x16x32_bf16(W[8 + kk], a, acc1, 0, 0, 0);
        }
        float* op = orow + (size_t)k * 16 * OSTRIDE;
        *reinterpret_cast<f32x4*>(op) = acc0;
        *reinterpret_cast<f32x4*>(op + 16) = acc1;
    }
#undef STAGE
#undef VMW
}

extern "C" void kernel_launch(void* const* d_in, const int* in_sizes, int n_in,
                              void* d_out, int out_size, void* d_ws, size_t ws_size,
                              hipStream_t stream) {
    const float* x    = (const float*)d_in[0];
    const float* w    = (const float*)d_in[1];
    const float* bias = (const float*)d_in[2];
    float* out = (float*)d_out;

    __bf16* xb = (__bf16*)d_ws;                      // 8192*256 bf16 = 4 MB
    __bf16* wb = xb + (size_t)B_ROWS * IN_DIM;       // 50*32*256 bf16 = 0.8 MB

    prep<<<NCLS + CVT_BLOCKS, 256, 0, stream>>>(x, w, xb, wb);
    gemm<<<GGRID, 256, 0, stream>>>(xb, wb, bias, out);
}

// Round 17
// 29.101 us; speedup vs baseline: 1.1832x; 1.1832x over previous
//
#include <hip/hip_runtime.h>
#include <hip/hip_bf16.h>

typedef __bf16 bf16x8 __attribute__((ext_vector_type(8)));
typedef float  f32x4  __attribute__((ext_vector_type(4)));

#define B_ROWS 8192
#define IN_DIM 256
#define OUT_DIM 32
#define NCLS 50
#define INV_T (1.0f / 0.6f)

#define CVT_BLOCKS 1024  // x cvt: 8192*256 / (256*8)
#define ROWTILES 32      // 8192 / 256 rows per block
#define NCHUNK 4         // 64 rows/wave / 16

__device__ __forceinline__ void gload_lds16(const void* g, void* l) {
    __builtin_amdgcn_global_load_lds(
        (const __attribute__((address_space(1))) void*)g,
        (__attribute__((address_space(3))) void*)l, 16, 0, 0);
}

// prep (r14 verbatim): blocks [0,50) W-class; blocks [50,1074) x cvt.
__global__ __launch_bounds__(256) void prep(const float* __restrict__ x,
                                            const float* __restrict__ w,
                                            __bf16* __restrict__ xb,
                                            __bf16* __restrict__ wb) {
    __shared__ float wm[4];
    int bid = blockIdx.x;
    if (bid < NCLS) {
        int c = bid;
        int i = threadIdx.x;
        const float* wc = w + (size_t)c * OUT_DIM * IN_DIM + i;
        float wv[OUT_DIM];
#pragma unroll
        for (int o = 0; o < OUT_DIM; ++o) wv[o] = wc[o * IN_DIM];
        float gsum = 0.f;
#pragma unroll
        for (int o = 0; o < OUT_DIM; ++o) gsum += fabsf(wv[o]);
        float m = gsum;
#pragma unroll
        for (int s = 1; s < 64; s <<= 1) m = fmaxf(m, __shfl_xor(m, s));
        if ((threadIdx.x & 63) == 0) wm[threadIdx.x >> 6] = m;
        __syncthreads();
        m = fmaxf(fmaxf(wm[0], wm[1]), fmaxf(wm[2], wm[3]));
        float an = __expf((gsum - m) * INV_T);
        __bf16* wo = wb + (size_t)c * OUT_DIM * IN_DIM + i;
#pragma unroll
        for (int o = 0; o < OUT_DIM; ++o)
            wo[o * IN_DIM] = (__bf16)(wv[o] * an);
    } else {
        int i = ((bid - NCLS) * 256 + threadIdx.x) * 8;
        float4 v0 = *reinterpret_cast<const float4*>(x + i);
        float4 v1 = *reinterpret_cast<const float4*>(x + i + 4);
        bf16x8 r;
        r[0] = (__bf16)v0.x; r[1] = (__bf16)v0.y; r[2] = (__bf16)v0.z; r[3] = (__bf16)v0.w;
        r[4] = (__bf16)v1.x; r[5] = (__bf16)v1.y; r[6] = (__bf16)v1.z; r[7] = (__bf16)v1.w;
        *reinterpret_cast<bf16x8*>(xb + i) = r;
    }
}

// GEMM (r14 structure, 256-row blocks): out[b,c,o] = sum_i xb*wb + bias
// grid = 25 class-pairs * 32 row-tiles = 800 (finer blocks -> makespan
// 1.625 vs 2.0 block-units at 2 blocks/CU; same-rows blocks stay 32 apart
// => same XCD => A-staging stays L2-local). Block = 4 waves, 256 rows,
// 2 classes; wave = 64 rows = 4 chunks of 16.
// W' slab (32 KB) staged into the Abuf1 union; 128 pinned VGPRs.
// Counted vmcnt: 12 = 8 next-chunk loads + 4 stores; last chunk 4.
// LDS swizzle (both-sides): phys 16B-slot s of row r holds logical s^(r&15).
__global__ __launch_bounds__(256, 2) void gemm(const __bf16* __restrict__ xb,
                                               const __bf16* __restrict__ wb,
                                               const float* __restrict__ bias,
                                               float* __restrict__ out) {
    __shared__ __align__(16) char lds[4 * 2 * 8192];  // 4 waves * {Abuf0, Abuf1}

    int bid = blockIdx.x;
    int cp = bid >> 5;           // 0..24
    int rt = bid & (ROWTILES - 1);
    int c0 = cp * 2;
    int row0 = rt * 256;
    int lane = threadIdx.x & 63;
    int w4 = threadIdx.x >> 6;
    int l15 = lane & 15;
    int g = lane >> 4;
    int s31 = lane & 31;
    int lr = lane >> 5;          // 0/1

    char* Abuf0 = lds + w4 * 16384;
    char* Abuf1 = Abuf0 + 8192;

    // --- stage A chunk 0 (wave-private 16 rows = 8 KB) into Abuf0 ---
    const char* arows = (const char*)(xb + (size_t)(row0 + w4 * 64) * IN_DIM);
#define STAGE_A(BUF, CHUNK)                                                       \
    _Pragma("unroll") for (int il = 0; il < 8; ++il) {                            \
        int r = (CHUNK) * 16 + 2 * il + lr;                                       \
        gload_lds16(arows + (size_t)r * 512 + ((s31 ^ (r & 15)) * 16),            \
                    (BUF) + il * 1024);                                           \
    }
    STAGE_A(Abuf0, 0)

    // --- stage W' pair (32 KB = 64 rows) into the Abuf1 regions ---
    const char* wsrc = (const char*)(wb + (size_t)c0 * OUT_DIM * IN_DIM);
#pragma unroll
    for (int jw = 0; jw < 8; ++jw) {
        int re = jw * 8 + w4 * 2;              // even row of this instr
        int r = re + lr;
        gload_lds16(wsrc + (size_t)r * 512 + ((s31 ^ (r & 15)) * 16),
                    lds + (re >> 4) * 16384 + 8192 + (re & 15) * 512);
    }

    asm volatile("s_waitcnt vmcnt(0)" ::: "memory");
    __syncthreads();
    __builtin_amdgcn_sched_barrier(0);

    // --- W' -> regs (swizzled ds_read); W row = ci*32 + l15 (+16) ---
    bf16x8 W[2][16];
#pragma unroll
    for (int ci = 0; ci < 2; ++ci)
#pragma unroll
        for (int kk = 0; kk < 8; ++kk) {
            int slot = (4 * kk + g) ^ l15;
            W[ci][kk]     = *reinterpret_cast<const bf16x8*>(
                lds + (2 * ci) * 16384 + 8192 + l15 * 512 + slot * 16);
            W[ci][8 + kk] = *reinterpret_cast<const bf16x8*>(
                lds + (2 * ci + 1) * 16384 + 8192 + l15 * 512 + slot * 16);
        }
#pragma unroll
    for (int ci = 0; ci < 2; ++ci)
#pragma unroll
        for (int kk = 0; kk < 16; ++kk)
            asm volatile("" : "+v"(W[ci][kk]));
    __builtin_amdgcn_sched_barrier(0);
    __syncthreads();   // all waves done reading W before chunk 1 stages Abuf1

    f32x4 bv00 = *reinterpret_cast<const f32x4*>(bias + c0 * OUT_DIM + g * 4);
    f32x4 bv01 = *reinterpret_cast<const f32x4*>(bias + c0 * OUT_DIM + 16 + g * 4);
    f32x4 bv10 = *reinterpret_cast<const f32x4*>(bias + (c0 + 1) * OUT_DIM + g * 4);
    f32x4 bv11 = *reinterpret_cast<const f32x4*>(bias + (c0 + 1) * OUT_DIM + 16 + g * 4);

    float* orow = out + (size_t)(row0 + w4 * 64 + l15) * (NCLS * OUT_DIM) + c0 * OUT_DIM + g * 4;

    // --- main loop: 4 chunks of 16 rows, 2 classes each ---
#pragma unroll
    for (int k = 0; k < NCHUNK; ++k) {
        char* cur = (k & 1) ? Abuf1 : Abuf0;
        char* nxt = (k & 1) ? Abuf0 : Abuf1;
        if (k + 1 < NCHUNK) {
            STAGE_A(nxt, k + 1)
            asm volatile("s_waitcnt vmcnt(12)" ::: "memory");
        } else {
            asm volatile("s_waitcnt vmcnt(4)" ::: "memory");
        }
        __builtin_amdgcn_sched_barrier(0);

        f32x4 acc00 = bv00;
        f32x4 acc01 = bv01;
        f32x4 acc10 = bv10;
        f32x4 acc11 = bv11;
#pragma unroll
        for (int kk = 0; kk < 8; ++kk) {
            int slot = (4 * kk + g) ^ l15;
            bf16x8 a = *reinterpret_cast<const bf16x8*>(cur + (size_t)l15 * 512 + slot * 16);
            acc00 = __builtin_amdgcn_mfma_f32_16x16x32_bf16(W[0][kk],     a, acc00, 0, 0, 0);
            acc01 = __builtin_amdgcn_mfma_f32_16x16x32_bf16(W[0][8 + kk], a, acc01, 0, 0, 0);
            acc10 = __builtin_amdgcn_mfma_f32_16x16x32_bf16(W[1][kk],     a, acc10, 0, 0, 0);
            acc11 = __builtin_amdgcn_mfma_f32_16x16x32_bf16(W[1][8 + kk], a, acc11, 0, 0, 0);
        }
        float* op = orow + (size_t)k * 16 * (NCLS * OUT_DIM);
        *reinterpret_cast<f32x4*>(op) = acc00;
        *reinterpret_cast<f32x4*>(op + 16) = acc01;
        *reinterpret_cast<f32x4*>(op + OUT_DIM) = acc10;
        *reinterpret_cast<f32x4*>(op + OUT_DIM + 16) = acc11;
    }
#undef STAGE_A
}

extern "C" void kernel_launch(void* const* d_in, const int* in_sizes, int n_in,
                              void* d_out, int out_size, void* d_ws, size_t ws_size,
                              hipStream_t stream) {
    const float* x    = (const float*)d_in[0];
    const float* w    = (const float*)d_in[1];
    const float* bias = (const float*)d_in[2];
    float* out = (float*)d_out;

    __bf16* xb = (__bf16*)d_ws;                      // 8192*256 bf16 = 4 MB
    __bf16* wb = xb + (size_t)B_ROWS * IN_DIM;       // 50*32*256 bf16 = 0.8 MB

    prep<<<NCLS + CVT_BLOCKS, 256, 0, stream>>>(x, w, xb, wb);
    gemm<<<25 * ROWTILES, 256, 0, stream>>>(xb, wb, bias, out);
}